// Round 7
// baseline (236.608 us; speedup 1.0000x reference)
//
#include <hip/hip_runtime.h>

#define IN_DIM 128
#define OUT_DIM 128
#define NUM_RELS 8
#define SCAN_ELEMS 2048   // per block, 256 thr x 8

typedef unsigned short u16;
typedef u16 u16x8 __attribute__((ext_vector_type(8)));
typedef u16 u16x4 __attribute__((ext_vector_type(4)));
typedef __bf16 bf16x8 __attribute__((ext_vector_type(8)));
typedef float f32x4 __attribute__((ext_vector_type(4)));

__device__ __forceinline__ u16 f2bf(float f) {
    unsigned u = __float_as_uint(f);
    u += 0x7FFF + ((u >> 16) & 1);      // RNE
    return (u16)(u >> 16);
}
__device__ __forceinline__ float bf2f(u16 h) {
    return __uint_as_float((unsigned)h << 16);
}

// ---------- fused prep: cast x -> bf16, cast+transpose W -> WbT, zero cursor ----------
__global__ __launch_bounds__(256) void k_prep(
    const float* __restrict__ x, const float* __restrict__ weight,
    const float* __restrict__ slw,
    u16* __restrict__ xb, u16* __restrict__ WbT, int* __restrict__ cursor,
    int N, int BA, int BB)
{
    const int b = blockIdx.x;
    const int tid = threadIdx.x;
    if (b < BA) {
        long i = ((long)b * 256 + tid) * 4;
        if (i < (long)N * 128) {
            float4 v = *(const float4*)(x + i);
            u16x4 o;
            o[0] = f2bf(v.x); o[1] = f2bf(v.y); o[2] = f2bf(v.z); o[3] = f2bf(v.w);
            *(u16x4*)(xb + i) = o;
        }
    } else if (b < BA + BB) {
        int t = (b - BA) * 256 + tid;            // t < 9*4096
        int z = t >> 12;
        int rem = t & 4095;
        int kk = rem >> 5;                        // k row 0..127
        int c0 = (rem & 31) * 4;                  // col group
        const float* srcp = (z < 8) ? (weight + (size_t)z * 16384 + kk * 128 + c0)
                                    : (slw + kk * 128 + c0);
        float4 v = *(const float4*)srcp;
        u16* outz = WbT + (size_t)z * 16384;
        outz[(c0 + 0) * 128 + kk] = f2bf(v.x);
        outz[(c0 + 1) * 128 + kk] = f2bf(v.y);
        outz[(c0 + 2) * 128 + kk] = f2bf(v.z);
        outz[(c0 + 3) * 128 + kk] = f2bf(v.w);
    } else {
        int j = (b - BA - BB) * 256 + tid;
        if (j < N) cursor[j] = 0;
    }
}

// ---------- MFMA GEMM v4: persistent blocks + register B-frags from WbT ----------
// grid (84,1,9) x 256 thr (4 waves), 3 blocks/CU. Wave: 64 rows x 64 cols.
// B-frags loaded once per block (vectorized from pre-transposed WbT),
// A direct from global (lockstep z-slabs keep xb L2-hot),
// wave-private LDS epilogue slab, no __syncthreads.
__global__ __launch_bounds__(256, 3) void mfma_gemm4(
    const u16* __restrict__ xb,    // [N][128] bf16
    const u16* __restrict__ WbT,   // [9][128(col)][128(k)] bf16
    const float* __restrict__ bias,
    u16* __restrict__ hr,          // [9][N][128] bf16
    int N, int ntiles)
{
    __shared__ u16 slab[4][16 * 68];

    const int tid   = threadIdx.x;
    const int z     = blockIdx.z;
    const int wv    = tid >> 6;
    const int lane  = tid & 63;
    const int q     = lane >> 4;
    const int l     = lane & 15;
    const int mbase = (wv >> 1) * 64;
    const int cbase = (wv & 1) * 64;

    const u16* Wz = WbT + (size_t)z * 16384;

    // B-frags: lane holds WbT[col=cbase+nt*16+l][kc*32+q*8 .. +7] (contiguous 16B)
    u16x8 Bf[4][4];
    #pragma unroll
    for (int nt = 0; nt < 4; ++nt) {
        const u16* colp = Wz + (cbase + nt * 16 + l) * 128;
        #pragma unroll
        for (int kc = 0; kc < 4; ++kc)
            Bf[nt][kc] = *(const u16x8*)(colp + kc * 32 + q * 8);
    }

    float bv[4];
    #pragma unroll
    for (int nt = 0; nt < 4; ++nt)
        bv[nt] = (z == 8) ? bias[cbase + nt * 16 + l] : 0.f;

    u16* slabw = &slab[wv][0];
    u16* hrz = hr + ((size_t)z * N) * 128;

    for (int tile = blockIdx.x; tile < ntiles; tile += gridDim.x) {
        const int n0 = tile * 128;

        f32x4 acc[4][4] = {};
        #pragma unroll
        for (int kc = 0; kc < 4; ++kc) {
            const int k0 = kc * 32 + q * 8;
            u16x8 a[4];
            #pragma unroll
            for (int mt = 0; mt < 4; ++mt) {
                const int row = n0 + mbase + mt * 16 + l;
                u16x8 v = {};
                if (row < N) v = *(const u16x8*)(xb + (size_t)row * 128 + k0);
                a[mt] = v;
            }
            #pragma unroll
            for (int nt = 0; nt < 4; ++nt) {
                bf16x8 b = __builtin_bit_cast(bf16x8, Bf[nt][kc]);
                #pragma unroll
                for (int mt = 0; mt < 4; ++mt) {
                    acc[mt][nt] = __builtin_amdgcn_mfma_f32_16x16x32_bf16(
                        __builtin_bit_cast(bf16x8, a[mt]), b, acc[mt][nt], 0, 0, 0);
                }
            }
        }

        #pragma unroll
        for (int mt = 0; mt < 4; ++mt) {
            #pragma unroll
            for (int nt = 0; nt < 4; ++nt) {
                const int col = nt * 16 + l;
                #pragma unroll
                for (int j = 0; j < 4; ++j)
                    slabw[(q * 4 + j) * 68 + col] = f2bf(acc[mt][nt][j] + bv[nt]);
            }
            const int srow = lane >> 3;
            const int scol = (lane & 7) * 8;
            #pragma unroll
            for (int h = 0; h < 2; ++h) {
                const int r = h * 8 + srow;
                const int grow = n0 + mbase + mt * 16 + r;
                if (grow < N) {
                    u16x8 v = *(const u16x8*)&slabw[r * 68 + scol];
                    *(u16x8*)(hrz + (size_t)grow * 128 + cbase + scol) = v;
                }
            }
        }
    }
}

// ---------- CSR build ----------
__global__ __launch_bounds__(256) void k_hist(
    const int* __restrict__ dst, int* __restrict__ deg, int E)
{
    int e = blockIdx.x * blockDim.x + threadIdx.x;
    if (e < E) atomicAdd(&deg[dst[e]], 1);
}

__global__ __launch_bounds__(256) void k_scan1(
    const int* __restrict__ deg, int* __restrict__ local,
    int* __restrict__ bsum, int n)
{
    __shared__ int s[256];
    const int t = threadIdx.x;
    const int base = blockIdx.x * SCAN_ELEMS + t * 8;
    int v[8];
    int sum = 0;
    #pragma unroll
    for (int j = 0; j < 8; ++j) {
        int i = base + j;
        v[j] = (i < n) ? deg[i] : 0;
        sum += v[j];
    }
    s[t] = sum;
    __syncthreads();
    #pragma unroll
    for (int off = 1; off < 256; off <<= 1) {
        int y = (t >= off) ? s[t - off] : 0;
        __syncthreads();
        s[t] += y;
        __syncthreads();
    }
    int run = s[t] - sum;
    #pragma unroll
    for (int j = 0; j < 8; ++j) {
        int i = base + j;
        if (i < n) local[i] = run;
        run += v[j];
    }
    if (t == 255) bsum[blockIdx.x] = s[255];
}

__global__ __launch_bounds__(256) void k_scan2(
    int* __restrict__ bsum, int* __restrict__ row_ptr, int B, int n)
{
    __shared__ int s[256];
    const int t = threadIdx.x;
    int v = (t < B) ? bsum[t] : 0;
    s[t] = v;
    __syncthreads();
    #pragma unroll
    for (int off = 1; off < 256; off <<= 1) {
        int y = (t >= off) ? s[t - off] : 0;
        __syncthreads();
        s[t] += y;
        __syncthreads();
    }
    if (t < B) bsum[t] = s[t] - v;
    if (t == 255) row_ptr[n] = s[255];
}

__global__ __launch_bounds__(256) void k_scan3(
    int* __restrict__ row_ptr, const int* __restrict__ bsum,
    int* __restrict__ cursor, int n)
{
    const int t = threadIdx.x;
    const int base = blockIdx.x * SCAN_ELEMS + t * 8;
    const int off = bsum[blockIdx.x];
    #pragma unroll
    for (int j = 0; j < 8; ++j) {
        int i = base + j;
        if (i < n) {
            int val = row_ptr[i] + off;
            row_ptr[i] = val;
            cursor[i] = val;
        }
    }
}

__global__ __launch_bounds__(256) void k_fill(
    const int* __restrict__ src, const int* __restrict__ dst,
    const int* __restrict__ et, int* __restrict__ cursor,
    int* __restrict__ packed, int E)
{
    int e = blockIdx.x * blockDim.x + threadIdx.x;
    if (e >= E) return;
    int pos = atomicAdd(&cursor[dst[e]], 1);
    packed[pos] = (et[e] << 17) | src[e];
}

// ---------- pull-based aggregate (bf16 hr), 4-deep MLP ----------
__global__ __launch_bounds__(256) void gather_bf16(
    const u16* __restrict__ hr,      // [8][N][128] bf16
    const u16* __restrict__ hself,   // [N][128] bf16 (x@slw + bias)
    const int* __restrict__ row_ptr, const int* __restrict__ packed,
    float* __restrict__ out, int Nn, int N)
{
    int g = blockIdx.x * 8 + (threadIdx.x >> 5);
    int lane = threadIdx.x & 31;
    if (g >= Nn) return;
    const int beg = row_ptr[g];
    const int end = row_ptr[g + 1];

    u16x4 s = *(const u16x4*)(hself + (size_t)g * 128 + lane * 4);
    float a0 = bf2f(s[0]), a1 = bf2f(s[1]), a2 = bf2f(s[2]), a3 = bf2f(s[3]);
    float b0 = 0.f, b1 = 0.f, b2 = 0.f, b3 = 0.f;
    float c0 = 0.f, c1 = 0.f, c2 = 0.f, c3 = 0.f;
    float d0 = 0.f, d1 = 0.f, d2 = 0.f, d3 = 0.f;

    const int lo = lane * 4;
    int k = beg;
    for (; k + 4 <= end; k += 4) {
        int p0 = packed[k], p1 = packed[k + 1], p2 = packed[k + 2], p3 = packed[k + 3];
        u16x4 v0 = *(const u16x4*)(hr + ((size_t)(p0 >> 17) * N + (p0 & 0x1FFFF)) * 128 + lo);
        u16x4 v1 = *(const u16x4*)(hr + ((size_t)(p1 >> 17) * N + (p1 & 0x1FFFF)) * 128 + lo);
        u16x4 v2 = *(const u16x4*)(hr + ((size_t)(p2 >> 17) * N + (p2 & 0x1FFFF)) * 128 + lo);
        u16x4 v3 = *(const u16x4*)(hr + ((size_t)(p3 >> 17) * N + (p3 & 0x1FFFF)) * 128 + lo);
        a0 += bf2f(v0[0]); a1 += bf2f(v0[1]); a2 += bf2f(v0[2]); a3 += bf2f(v0[3]);
        b0 += bf2f(v1[0]); b1 += bf2f(v1[1]); b2 += bf2f(v1[2]); b3 += bf2f(v1[3]);
        c0 += bf2f(v2[0]); c1 += bf2f(v2[1]); c2 += bf2f(v2[2]); c3 += bf2f(v2[3]);
        d0 += bf2f(v3[0]); d1 += bf2f(v3[1]); d2 += bf2f(v3[2]); d3 += bf2f(v3[3]);
    }
    for (; k < end; ++k) {
        int p = packed[k];
        u16x4 v = *(const u16x4*)(hr + ((size_t)(p >> 17) * N + (p & 0x1FFFF)) * 128 + lo);
        a0 += bf2f(v[0]); a1 += bf2f(v[1]); a2 += bf2f(v[2]); a3 += bf2f(v[3]);
    }
    a0 += b0 + c0 + d0; a1 += b1 + c1 + d1;
    a2 += b2 + c2 + d2; a3 += b3 + c3 + d3;

    float4 o = make_float4(fmaxf(a0, 0.f), fmaxf(a1, 0.f),
                           fmaxf(a2, 0.f), fmaxf(a3, 0.f));
    *(float4*)(out + (size_t)g * 128 + lane * 4) = o;
}

// ---------- fp32 fallback kernels ----------
__global__ __launch_bounds__(256) void gemm128(
    const float* __restrict__ x, const float* __restrict__ W,
    const float* __restrict__ bias, float* __restrict__ out, int N)
{
    __shared__ float Ws[IN_DIM * OUT_DIM];
    __shared__ float xs[16][IN_DIM];

    const float* Wz = W + (size_t)blockIdx.z * IN_DIM * OUT_DIM;
    float* outz = out + (size_t)blockIdx.z * (size_t)N * OUT_DIM;

    {
        const float4* s4 = (const float4*)Wz;
        float4* d4 = (float4*)Ws;
        for (int i = threadIdx.x; i < IN_DIM * OUT_DIM / 4; i += 256)
            d4[i] = s4[i];
    }

    const int tid = threadIdx.x;
    const int nl = (tid >> 5) * 2;
    const int og = (tid & 31) * 4;

    float4 b4 = make_float4(0.f, 0.f, 0.f, 0.f);
    if (bias) b4 = *(const float4*)&bias[og];

    const int nchunks = (N + 15) / 16;
    for (int chunk = blockIdx.x; chunk < nchunks; chunk += gridDim.x) {
        const int n0 = chunk * 16;
        const int rows = min(16, N - n0);
        __syncthreads();
        {
            const float4* xsrc = (const float4*)(x + (size_t)n0 * IN_DIM);
            float4* xdst = (float4*)&xs[0][0];
            const int n4 = rows * (IN_DIM / 4);
            for (int i = tid; i < n4; i += 256) xdst[i] = xsrc[i];
        }
        __syncthreads();

        if (nl < rows) {
            float a00 = 0.f, a01 = 0.f, a02 = 0.f, a03 = 0.f;
            float a10 = 0.f, a11 = 0.f, a12 = 0.f, a13 = 0.f;
            #pragma unroll 8
            for (int d = 0; d < IN_DIM; ++d) {
                const float4 w4 = *(const float4*)&Ws[d * OUT_DIM + og];
                const float xa = xs[nl][d];
                const float xb = xs[nl + 1][d];
                a00 += xa * w4.x; a01 += xa * w4.y; a02 += xa * w4.z; a03 += xa * w4.w;
                a10 += xb * w4.x; a11 += xb * w4.y; a12 += xb * w4.z; a13 += xb * w4.w;
            }
            float4 r0 = make_float4(a00 + b4.x, a01 + b4.y, a02 + b4.z, a03 + b4.w);
            *(float4*)&outz[(size_t)(n0 + nl) * OUT_DIM + og] = r0;
            if (nl + 1 < rows) {
                float4 r1 = make_float4(a10 + b4.x, a11 + b4.y, a12 + b4.z, a13 + b4.w);
                *(float4*)&outz[(size_t)(n0 + nl + 1) * OUT_DIM + og] = r1;
            }
        }
    }
}

__global__ __launch_bounds__(256) void edge_direct(
    const float* __restrict__ x, const float* __restrict__ W,
    const int* __restrict__ src, const int* __restrict__ dst,
    const int* __restrict__ et, float* __restrict__ out, int E)
{
    long t = (long)blockIdx.x * blockDim.x + threadIdx.x;
    long e = t >> 6;
    int lane = (int)(t & 63);
    if (e >= E) return;
    int s = src[e], d = dst[e], r = et[e];
    const float* xr = x + (long)s * IN_DIM;
    float2 xv = *(const float2*)(xr + lane * 2);
    const float* Wr = W + (long)r * IN_DIM * OUT_DIM;
    const int o0 = lane * 2;
    float a0 = 0.f, a1 = 0.f;
    #pragma unroll 8
    for (int dd = 0; dd < 64; ++dd) {
        float xa = __shfl(xv.x, dd);
        float xb = __shfl(xv.y, dd);
        a0 += xa * Wr[(2 * dd) * OUT_DIM + o0]     + xb * Wr[(2 * dd + 1) * OUT_DIM + o0];
        a1 += xa * Wr[(2 * dd) * OUT_DIM + o0 + 1] + xb * Wr[(2 * dd + 1) * OUT_DIM + o0 + 1];
    }
    atomicAdd(out + (long)d * OUT_DIM + o0, a0);
    atomicAdd(out + (long)d * OUT_DIM + o0 + 1, a1);
}

__global__ __launch_bounds__(256) void relu_k(float* __restrict__ out, long n4)
{
    long i = (long)blockIdx.x * blockDim.x + threadIdx.x;
    if (i >= n4) return;
    float4 v = ((float4*)out)[i];
    v.x = fmaxf(v.x, 0.f); v.y = fmaxf(v.y, 0.f);
    v.z = fmaxf(v.z, 0.f); v.w = fmaxf(v.w, 0.f);
    ((float4*)out)[i] = v;
}

static inline size_t align256(size_t x) { return (x + 255) & ~(size_t)255; }

extern "C" void kernel_launch(void* const* d_in, const int* in_sizes, int n_in,
                              void* d_out, int out_size, void* d_ws, size_t ws_size,
                              hipStream_t stream)
{
    const float* x      = (const float*)d_in[0];
    const float* weight = (const float*)d_in[1];
    const float* slw    = (const float*)d_in[2];
    const float* bias   = (const float*)d_in[3];
    const int*   ei     = (const int*)d_in[4];
    const int*   et     = (const int*)d_in[5];

    const int N = in_sizes[0] / IN_DIM;
    const int E = in_sizes[5];
    const int* src  = ei;
    const int* dstp = ei + E;

    float* out = (float*)d_out;

    // workspace layout (bf16 path)
    size_t off = 0;
    const size_t xb_off   = off; off += align256((size_t)N * 128 * 2);
    const size_t wb_off   = off; off += align256((size_t)9 * 128 * 128 * 2);
    const size_t hr_off   = off; off += align256((size_t)9 * N * 128 * 2);
    const size_t rp_off   = off; off += align256((size_t)(N + 1) * 4);
    const size_t cur_off  = off; off += align256((size_t)N * 4);
    const size_t pk_off   = off; off += align256((size_t)E * 4);
    const size_t bs_off   = off; off += align256(256 * 4);
    const size_t need_bf16 = off;

    const int scanB = (N + SCAN_ELEMS - 1) / SCAN_ELEMS;

    if (ws_size >= need_bf16 && N <= (1 << 17) && scanB <= 256) {
        char* base   = (char*)d_ws;
        u16* xb      = (u16*)(base + xb_off);
        u16* WbT     = (u16*)(base + wb_off);
        u16* hr      = (u16*)(base + hr_off);
        int* row_ptr = (int*)(base + rp_off);
        int* cursor  = (int*)(base + cur_off);
        int* packed  = (int*)(base + pk_off);
        int* bsum    = (int*)(base + bs_off);

        // fused prep: cast x, cast+transpose W, zero cursor
        const int BA = (int)(((long)N * 128 / 4 + 255) / 256);
        const int BB = 9 * 4096 / 256;      // 144
        const int BC = (N + 255) / 256;
        k_prep<<<dim3(BA + BB + BC), 256, 0, stream>>>(
            x, weight, slw, xb, WbT, cursor, N, BA, BB);

        // CSR build (deg lives in cursor)
        k_hist<<<dim3((E + 255) / 256), 256, 0, stream>>>(dstp, cursor, E);
        k_scan1<<<dim3(scanB), 256, 0, stream>>>(cursor, row_ptr, bsum, N);
        k_scan2<<<dim3(1), 256, 0, stream>>>(bsum, row_ptr, scanB, N);
        k_scan3<<<dim3(scanB), 256, 0, stream>>>(row_ptr, bsum, cursor, N);
        k_fill<<<dim3((E + 255) / 256), 256, 0, stream>>>(src, dstp, et, cursor, packed, E);

        // all 9 transforms via MFMA: persistent blocks, 3/CU, lockstep z
        const int ntiles = (N + 127) / 128;
        const int gx = ntiles < 84 ? ntiles : 84;
        mfma_gemm4<<<dim3(gx, 1, 9), 256, 0, stream>>>(xb, WbT, bias, hr, N, ntiles);

        // aggregate + self + relu -> out
        gather_bf16<<<dim3((N + 7) / 8), 256, 0, stream>>>(
            hr, hr + (size_t)8 * N * 128, row_ptr, packed, out, N, N);
    } else if (ws_size >= (size_t)NUM_RELS * N * 128 * 4) {
        gemm128<<<dim3(512, 1, 1), 256, 0, stream>>>(x, slw, bias, out, N);
        long nt = (long)E * 64;
        edge_direct<<<dim3((nt + 255) / 256), 256, 0, stream>>>(x, weight, src, dstp, et, out, E);
        long n4 = (long)N * OUT_DIM / 4;
        relu_k<<<dim3((n4 + 255) / 256), 256, 0, stream>>>(out, n4);
    } else {
        gemm128<<<dim3(512, 1, 1), 256, 0, stream>>>(x, slw, bias, out, N);
        long nt = (long)E * 64;
        edge_direct<<<dim3((nt + 255) / 256), 256, 0, stream>>>(x, weight, src, dstp, et, out, E);
        long n4 = (long)N * OUT_DIM / 4;
        relu_k<<<dim3((n4 + 255) / 256), 256, 0, stream>>>(out, n4);
    }
}

// Round 8
// 231.837 us; speedup vs baseline: 1.0206x; 1.0206x over previous
//
#include <hip/hip_runtime.h>

#define IN_DIM 128
#define OUT_DIM 128
#define NUM_RELS 8
#define SCAN_ELEMS 2048   // per block, 256 thr x 8

typedef unsigned short u16;
typedef u16 u16x8 __attribute__((ext_vector_type(8)));
typedef u16 u16x4 __attribute__((ext_vector_type(4)));
typedef __bf16 bf16x8 __attribute__((ext_vector_type(8)));
typedef float f32x4 __attribute__((ext_vector_type(4)));

__device__ __forceinline__ u16 f2bf(float f) {
    unsigned u = __float_as_uint(f);
    u += 0x7FFF + ((u >> 16) & 1);      // RNE
    return (u16)(u >> 16);
}
__device__ __forceinline__ float bf2f(u16 h) {
    return __uint_as_float((unsigned)h << 16);
}

// ---------- fused prep: cast x -> bf16, cast+transpose W -> WbT, zero cursor ----------
__global__ __launch_bounds__(256) void k_prep(
    const float* __restrict__ x, const float* __restrict__ weight,
    const float* __restrict__ slw,
    u16* __restrict__ xb, u16* __restrict__ WbT, int* __restrict__ cursor,
    int N, int BA, int BB)
{
    const int b = blockIdx.x;
    const int tid = threadIdx.x;
    if (b < BA) {
        long i = ((long)b * 256 + tid) * 4;
        if (i < (long)N * 128) {
            float4 v = *(const float4*)(x + i);
            u16x4 o;
            o[0] = f2bf(v.x); o[1] = f2bf(v.y); o[2] = f2bf(v.z); o[3] = f2bf(v.w);
            *(u16x4*)(xb + i) = o;
        }
    } else if (b < BA + BB) {
        int t = (b - BA) * 256 + tid;            // t < 9*4096
        int z = t >> 12;
        int rem = t & 4095;
        int kk = rem >> 5;                        // k row 0..127
        int c0 = (rem & 31) * 4;                  // col group
        const float* srcp = (z < 8) ? (weight + (size_t)z * 16384 + kk * 128 + c0)
                                    : (slw + kk * 128 + c0);
        float4 v = *(const float4*)srcp;
        u16* outz = WbT + (size_t)z * 16384;
        outz[(c0 + 0) * 128 + kk] = f2bf(v.x);
        outz[(c0 + 1) * 128 + kk] = f2bf(v.y);
        outz[(c0 + 2) * 128 + kk] = f2bf(v.z);
        outz[(c0 + 3) * 128 + kk] = f2bf(v.w);
    } else {
        int j = (b - BA - BB) * 256 + tid;
        if (j < N) cursor[j] = 0;
    }
}

// ---------- MFMA GEMM v5: CO-RESIDENT persistent blocks (grid 56x9=504) ----------
// All 9 z-slabs resident simultaneously -> lockstep tile loop keeps xb L2-hot
// (FETCH ~8 MB vs 57-69 MB when z-serialized; measured R5 vs R6/R7).
// B-frags vectorized from pre-transposed WbT, loaded once per block.
// Wave-private LDS epilogue slab, no __syncthreads.
__global__ __launch_bounds__(256, 3) void mfma_gemm5(
    const u16* __restrict__ xb,    // [N][128] bf16
    const u16* __restrict__ WbT,   // [9][128(col)][128(k)] bf16
    const float* __restrict__ bias,
    u16* __restrict__ hr,          // [9][N][128] bf16
    int N, int ntiles)
{
    __shared__ u16 slab[4][16 * 68];

    const int tid   = threadIdx.x;
    const int z     = blockIdx.z;
    const int wv    = tid >> 6;
    const int lane  = tid & 63;
    const int q     = lane >> 4;
    const int l     = lane & 15;
    const int mbase = (wv >> 1) * 64;
    const int cbase = (wv & 1) * 64;

    const u16* Wz = WbT + (size_t)z * 16384;

    // B-frags: lane holds WbT[col=cbase+nt*16+l][kc*32+q*8 .. +7] (contiguous 16B)
    u16x8 Bf[4][4];
    #pragma unroll
    for (int nt = 0; nt < 4; ++nt) {
        const u16* colp = Wz + (cbase + nt * 16 + l) * 128;
        #pragma unroll
        for (int kc = 0; kc < 4; ++kc)
            Bf[nt][kc] = *(const u16x8*)(colp + kc * 32 + q * 8);
    }

    float bv[4];
    #pragma unroll
    for (int nt = 0; nt < 4; ++nt)
        bv[nt] = (z == 8) ? bias[cbase + nt * 16 + l] : 0.f;

    u16* slabw = &slab[wv][0];
    u16* hrz = hr + ((size_t)z * N) * 128;

    for (int tile = blockIdx.x; tile < ntiles; tile += gridDim.x) {
        const int n0 = tile * 128;

        f32x4 acc[4][4] = {};
        #pragma unroll
        for (int kc = 0; kc < 4; ++kc) {
            const int k0 = kc * 32 + q * 8;
            u16x8 a[4];
            #pragma unroll
            for (int mt = 0; mt < 4; ++mt) {
                const int row = n0 + mbase + mt * 16 + l;
                u16x8 v = {};
                if (row < N) v = *(const u16x8*)(xb + (size_t)row * 128 + k0);
                a[mt] = v;
            }
            #pragma unroll
            for (int nt = 0; nt < 4; ++nt) {
                bf16x8 b = __builtin_bit_cast(bf16x8, Bf[nt][kc]);
                #pragma unroll
                for (int mt = 0; mt < 4; ++mt) {
                    acc[mt][nt] = __builtin_amdgcn_mfma_f32_16x16x32_bf16(
                        __builtin_bit_cast(bf16x8, a[mt]), b, acc[mt][nt], 0, 0, 0);
                }
            }
        }

        #pragma unroll
        for (int mt = 0; mt < 4; ++mt) {
            #pragma unroll
            for (int nt = 0; nt < 4; ++nt) {
                const int col = nt * 16 + l;
                #pragma unroll
                for (int j = 0; j < 4; ++j)
                    slabw[(q * 4 + j) * 68 + col] = f2bf(acc[mt][nt][j] + bv[nt]);
            }
            const int srow = lane >> 3;
            const int scol = (lane & 7) * 8;
            #pragma unroll
            for (int h = 0; h < 2; ++h) {
                const int r = h * 8 + srow;
                const int grow = n0 + mbase + mt * 16 + r;
                if (grow < N) {
                    u16x8 v = *(const u16x8*)&slabw[r * 68 + scol];
                    *(u16x8*)(hrz + (size_t)grow * 128 + cbase + scol) = v;
                }
            }
        }
    }
}

// ---------- CSR build ----------
__global__ __launch_bounds__(256) void k_hist(
    const int* __restrict__ dst, int* __restrict__ deg, int E)
{
    int e = blockIdx.x * blockDim.x + threadIdx.x;
    if (e < E) atomicAdd(&deg[dst[e]], 1);
}

__global__ __launch_bounds__(256) void k_scan1(
    const int* __restrict__ deg, int* __restrict__ local,
    int* __restrict__ bsum, int n)
{
    __shared__ int s[256];
    const int t = threadIdx.x;
    const int base = blockIdx.x * SCAN_ELEMS + t * 8;
    int v[8];
    int sum = 0;
    #pragma unroll
    for (int j = 0; j < 8; ++j) {
        int i = base + j;
        v[j] = (i < n) ? deg[i] : 0;
        sum += v[j];
    }
    s[t] = sum;
    __syncthreads();
    #pragma unroll
    for (int off = 1; off < 256; off <<= 1) {
        int y = (t >= off) ? s[t - off] : 0;
        __syncthreads();
        s[t] += y;
        __syncthreads();
    }
    int run = s[t] - sum;
    #pragma unroll
    for (int j = 0; j < 8; ++j) {
        int i = base + j;
        if (i < n) local[i] = run;
        run += v[j];
    }
    if (t == 255) bsum[blockIdx.x] = s[255];
}

__global__ __launch_bounds__(256) void k_scan2(
    int* __restrict__ bsum, int* __restrict__ row_ptr, int B, int n)
{
    __shared__ int s[256];
    const int t = threadIdx.x;
    int v = (t < B) ? bsum[t] : 0;
    s[t] = v;
    __syncthreads();
    #pragma unroll
    for (int off = 1; off < 256; off <<= 1) {
        int y = (t >= off) ? s[t - off] : 0;
        __syncthreads();
        s[t] += y;
        __syncthreads();
    }
    if (t < B) bsum[t] = s[t] - v;
    if (t == 255) row_ptr[n] = s[255];
}

__global__ __launch_bounds__(256) void k_scan3(
    int* __restrict__ row_ptr, const int* __restrict__ bsum,
    int* __restrict__ cursor, int n)
{
    const int t = threadIdx.x;
    const int base = blockIdx.x * SCAN_ELEMS + t * 8;
    const int off = bsum[blockIdx.x];
    #pragma unroll
    for (int j = 0; j < 8; ++j) {
        int i = base + j;
        if (i < n) {
            int val = row_ptr[i] + off;
            row_ptr[i] = val;
            cursor[i] = val;
        }
    }
}

__global__ __launch_bounds__(256) void k_fill(
    const int* __restrict__ src, const int* __restrict__ dst,
    const int* __restrict__ et, int* __restrict__ cursor,
    int* __restrict__ packed, int E)
{
    int e = blockIdx.x * blockDim.x + threadIdx.x;
    if (e >= E) return;
    int pos = atomicAdd(&cursor[dst[e]], 1);
    packed[pos] = (et[e] << 17) | src[e];
}

// ---------- pull-based aggregate (bf16 hr), 4-deep MLP ----------
__global__ __launch_bounds__(256) void gather_bf16(
    const u16* __restrict__ hr,      // [8][N][128] bf16
    const u16* __restrict__ hself,   // [N][128] bf16 (x@slw + bias)
    const int* __restrict__ row_ptr, const int* __restrict__ packed,
    float* __restrict__ out, int Nn, int N)
{
    int g = blockIdx.x * 8 + (threadIdx.x >> 5);
    int lane = threadIdx.x & 31;
    if (g >= Nn) return;
    const int beg = row_ptr[g];
    const int end = row_ptr[g + 1];

    u16x4 s = *(const u16x4*)(hself + (size_t)g * 128 + lane * 4);
    float a0 = bf2f(s[0]), a1 = bf2f(s[1]), a2 = bf2f(s[2]), a3 = bf2f(s[3]);
    float b0 = 0.f, b1 = 0.f, b2 = 0.f, b3 = 0.f;
    float c0 = 0.f, c1 = 0.f, c2 = 0.f, c3 = 0.f;
    float d0 = 0.f, d1 = 0.f, d2 = 0.f, d3 = 0.f;

    const int lo = lane * 4;
    int k = beg;
    for (; k + 4 <= end; k += 4) {
        int p0 = packed[k], p1 = packed[k + 1], p2 = packed[k + 2], p3 = packed[k + 3];
        u16x4 v0 = *(const u16x4*)(hr + ((size_t)(p0 >> 17) * N + (p0 & 0x1FFFF)) * 128 + lo);
        u16x4 v1 = *(const u16x4*)(hr + ((size_t)(p1 >> 17) * N + (p1 & 0x1FFFF)) * 128 + lo);
        u16x4 v2 = *(const u16x4*)(hr + ((size_t)(p2 >> 17) * N + (p2 & 0x1FFFF)) * 128 + lo);
        u16x4 v3 = *(const u16x4*)(hr + ((size_t)(p3 >> 17) * N + (p3 & 0x1FFFF)) * 128 + lo);
        a0 += bf2f(v0[0]); a1 += bf2f(v0[1]); a2 += bf2f(v0[2]); a3 += bf2f(v0[3]);
        b0 += bf2f(v1[0]); b1 += bf2f(v1[1]); b2 += bf2f(v1[2]); b3 += bf2f(v1[3]);
        c0 += bf2f(v2[0]); c1 += bf2f(v2[1]); c2 += bf2f(v2[2]); c3 += bf2f(v2[3]);
        d0 += bf2f(v3[0]); d1 += bf2f(v3[1]); d2 += bf2f(v3[2]); d3 += bf2f(v3[3]);
    }
    for (; k < end; ++k) {
        int p = packed[k];
        u16x4 v = *(const u16x4*)(hr + ((size_t)(p >> 17) * N + (p & 0x1FFFF)) * 128 + lo);
        a0 += bf2f(v[0]); a1 += bf2f(v[1]); a2 += bf2f(v[2]); a3 += bf2f(v[3]);
    }
    a0 += b0 + c0 + d0; a1 += b1 + c1 + d1;
    a2 += b2 + c2 + d2; a3 += b3 + c3 + d3;

    float4 o = make_float4(fmaxf(a0, 0.f), fmaxf(a1, 0.f),
                           fmaxf(a2, 0.f), fmaxf(a3, 0.f));
    *(float4*)(out + (size_t)g * 128 + lane * 4) = o;
}

// ---------- fp32 fallback kernels ----------
__global__ __launch_bounds__(256) void gemm128(
    const float* __restrict__ x, const float* __restrict__ W,
    const float* __restrict__ bias, float* __restrict__ out, int N)
{
    __shared__ float Ws[IN_DIM * OUT_DIM];
    __shared__ float xs[16][IN_DIM];

    const float* Wz = W + (size_t)blockIdx.z * IN_DIM * OUT_DIM;
    float* outz = out + (size_t)blockIdx.z * (size_t)N * OUT_DIM;

    {
        const float4* s4 = (const float4*)Wz;
        float4* d4 = (float4*)Ws;
        for (int i = threadIdx.x; i < IN_DIM * OUT_DIM / 4; i += 256)
            d4[i] = s4[i];
    }

    const int tid = threadIdx.x;
    const int nl = (tid >> 5) * 2;
    const int og = (tid & 31) * 4;

    float4 b4 = make_float4(0.f, 0.f, 0.f, 0.f);
    if (bias) b4 = *(const float4*)&bias[og];

    const int nchunks = (N + 15) / 16;
    for (int chunk = blockIdx.x; chunk < nchunks; chunk += gridDim.x) {
        const int n0 = chunk * 16;
        const int rows = min(16, N - n0);
        __syncthreads();
        {
            const float4* xsrc = (const float4*)(x + (size_t)n0 * IN_DIM);
            float4* xdst = (float4*)&xs[0][0];
            const int n4 = rows * (IN_DIM / 4);
            for (int i = tid; i < n4; i += 256) xdst[i] = xsrc[i];
        }
        __syncthreads();

        if (nl < rows) {
            float a00 = 0.f, a01 = 0.f, a02 = 0.f, a03 = 0.f;
            float a10 = 0.f, a11 = 0.f, a12 = 0.f, a13 = 0.f;
            #pragma unroll 8
            for (int d = 0; d < IN_DIM; ++d) {
                const float4 w4 = *(const float4*)&Ws[d * OUT_DIM + og];
                const float xa = xs[nl][d];
                const float xb = xs[nl + 1][d];
                a00 += xa * w4.x; a01 += xa * w4.y; a02 += xa * w4.z; a03 += xa * w4.w;
                a10 += xb * w4.x; a11 += xb * w4.y; a12 += xb * w4.z; a13 += xb * w4.w;
            }
            float4 r0 = make_float4(a00 + b4.x, a01 + b4.y, a02 + b4.z, a03 + b4.w);
            *(float4*)&outz[(size_t)(n0 + nl) * OUT_DIM + og] = r0;
            if (nl + 1 < rows) {
                float4 r1 = make_float4(a10 + b4.x, a11 + b4.y, a12 + b4.z, a13 + b4.w);
                *(float4*)&outz[(size_t)(n0 + nl + 1) * OUT_DIM + og] = r1;
            }
        }
    }
}

__global__ __launch_bounds__(256) void edge_direct(
    const float* __restrict__ x, const float* __restrict__ W,
    const int* __restrict__ src, const int* __restrict__ dst,
    const int* __restrict__ et, float* __restrict__ out, int E)
{
    long t = (long)blockIdx.x * blockDim.x + threadIdx.x;
    long e = t >> 6;
    int lane = (int)(t & 63);
    if (e >= E) return;
    int s = src[e], d = dst[e], r = et[e];
    const float* xr = x + (long)s * IN_DIM;
    float2 xv = *(const float2*)(xr + lane * 2);
    const float* Wr = W + (long)r * IN_DIM * OUT_DIM;
    const int o0 = lane * 2;
    float a0 = 0.f, a1 = 0.f;
    #pragma unroll 8
    for (int dd = 0; dd < 64; ++dd) {
        float xa = __shfl(xv.x, dd);
        float xb = __shfl(xv.y, dd);
        a0 += xa * Wr[(2 * dd) * OUT_DIM + o0]     + xb * Wr[(2 * dd + 1) * OUT_DIM + o0];
        a1 += xa * Wr[(2 * dd) * OUT_DIM + o0 + 1] + xb * Wr[(2 * dd + 1) * OUT_DIM + o0 + 1];
    }
    atomicAdd(out + (long)d * OUT_DIM + o0, a0);
    atomicAdd(out + (long)d * OUT_DIM + o0 + 1, a1);
}

__global__ __launch_bounds__(256) void relu_k(float* __restrict__ out, long n4)
{
    long i = (long)blockIdx.x * blockDim.x + threadIdx.x;
    if (i >= n4) return;
    float4 v = ((float4*)out)[i];
    v.x = fmaxf(v.x, 0.f); v.y = fmaxf(v.y, 0.f);
    v.z = fmaxf(v.z, 0.f); v.w = fmaxf(v.w, 0.f);
    ((float4*)out)[i] = v;
}

static inline size_t align256(size_t x) { return (x + 255) & ~(size_t)255; }

extern "C" void kernel_launch(void* const* d_in, const int* in_sizes, int n_in,
                              void* d_out, int out_size, void* d_ws, size_t ws_size,
                              hipStream_t stream)
{
    const float* x      = (const float*)d_in[0];
    const float* weight = (const float*)d_in[1];
    const float* slw    = (const float*)d_in[2];
    const float* bias   = (const float*)d_in[3];
    const int*   ei     = (const int*)d_in[4];
    const int*   et     = (const int*)d_in[5];

    const int N = in_sizes[0] / IN_DIM;
    const int E = in_sizes[5];
    const int* src  = ei;
    const int* dstp = ei + E;

    float* out = (float*)d_out;

    // workspace layout (bf16 path)
    size_t off = 0;
    const size_t xb_off   = off; off += align256((size_t)N * 128 * 2);
    const size_t wb_off   = off; off += align256((size_t)9 * 128 * 128 * 2);
    const size_t hr_off   = off; off += align256((size_t)9 * N * 128 * 2);
    const size_t rp_off   = off; off += align256((size_t)(N + 1) * 4);
    const size_t cur_off  = off; off += align256((size_t)N * 4);
    const size_t pk_off   = off; off += align256((size_t)E * 4);
    const size_t bs_off   = off; off += align256(256 * 4);
    const size_t need_bf16 = off;

    const int scanB = (N + SCAN_ELEMS - 1) / SCAN_ELEMS;

    if (ws_size >= need_bf16 && N <= (1 << 17) && scanB <= 256) {
        char* base   = (char*)d_ws;
        u16* xb      = (u16*)(base + xb_off);
        u16* WbT     = (u16*)(base + wb_off);
        u16* hr      = (u16*)(base + hr_off);
        int* row_ptr = (int*)(base + rp_off);
        int* cursor  = (int*)(base + cur_off);
        int* packed  = (int*)(base + pk_off);
        int* bsum    = (int*)(base + bs_off);

        // fused prep: cast x, cast+transpose W, zero cursor
        const int BA = (int)(((long)N * 128 / 4 + 255) / 256);
        const int BB = 9 * 4096 / 256;      // 144
        const int BC = (N + 255) / 256;
        k_prep<<<dim3(BA + BB + BC), 256, 0, stream>>>(
            x, weight, slw, xb, WbT, cursor, N, BA, BB);

        // CSR build (deg lives in cursor)
        k_hist<<<dim3((E + 255) / 256), 256, 0, stream>>>(dstp, cursor, E);
        k_scan1<<<dim3(scanB), 256, 0, stream>>>(cursor, row_ptr, bsum, N);
        k_scan2<<<dim3(1), 256, 0, stream>>>(bsum, row_ptr, scanB, N);
        k_scan3<<<dim3(scanB), 256, 0, stream>>>(row_ptr, bsum, cursor, N);
        k_fill<<<dim3((E + 255) / 256), 256, 0, stream>>>(src, dstp, et, cursor, packed, E);

        // all 9 transforms via MFMA: co-resident persistent grid (504 blocks)
        const int ntiles = (N + 127) / 128;
        const int gx = ntiles < 56 ? ntiles : 56;
        mfma_gemm5<<<dim3(gx, 1, 9), 256, 0, stream>>>(xb, WbT, bias, hr, N, ntiles);

        // aggregate + self + relu -> out
        gather_bf16<<<dim3((N + 7) / 8), 256, 0, stream>>>(
            hr, hr + (size_t)8 * N * 128, row_ptr, packed, out, N, N);
    } else if (ws_size >= (size_t)NUM_RELS * N * 128 * 4) {
        gemm128<<<dim3(512, 1, 1), 256, 0, stream>>>(x, slw, bias, out, N);
        long nt = (long)E * 64;
        edge_direct<<<dim3((nt + 255) / 256), 256, 0, stream>>>(x, weight, src, dstp, et, out, E);
        long n4 = (long)N * OUT_DIM / 4;
        relu_k<<<dim3((n4 + 255) / 256), 256, 0, stream>>>(out, n4);
    } else {
        gemm128<<<dim3(512, 1, 1), 256, 0, stream>>>(x, slw, bias, out, N);
        long nt = (long)E * 64;
        edge_direct<<<dim3((nt + 255) / 256), 256, 0, stream>>>(x, weight, src, dstp, et, out, E);
        long n4 = (long)N * OUT_DIM / 4;
        relu_k<<<dim3((n4 + 255) / 256), 256, 0, stream>>>(out, n4);
    }
}

// Round 9
// 211.027 us; speedup vs baseline: 1.1212x; 1.0986x over previous
//
#include <hip/hip_runtime.h>

#define IN_DIM 128
#define OUT_DIM 128
#define NUM_RELS 8
#define SCAN_ELEMS 2048   // per block, 256 thr x 8

typedef unsigned short u16;
typedef u16 u16x8 __attribute__((ext_vector_type(8)));
typedef u16 u16x4 __attribute__((ext_vector_type(4)));
typedef __bf16 bf16x8 __attribute__((ext_vector_type(8)));
typedef float f32x4 __attribute__((ext_vector_type(4)));

__device__ __forceinline__ u16 f2bf(float f) {
    unsigned u = __float_as_uint(f);
    u += 0x7FFF + ((u >> 16) & 1);      // RNE
    return (u16)(u >> 16);
}
__device__ __forceinline__ float bf2f(u16 h) {
    return __uint_as_float((unsigned)h << 16);
}

// ---------- fused prep: cast x -> bf16, cast W+slw -> Wb (ROW-MAJOR), zero cursor ----
__global__ __launch_bounds__(256) void k_prep(
    const float* __restrict__ x, const float* __restrict__ weight,
    const float* __restrict__ slw,
    u16* __restrict__ xb, u16* __restrict__ Wb, int* __restrict__ cursor,
    int N, int BA, int BB)
{
    const int b = blockIdx.x;
    const int tid = threadIdx.x;
    if (b < BA) {
        long i = ((long)b * 256 + tid) * 4;
        if (i < (long)N * 128) {
            float4 v = *(const float4*)(x + i);
            u16x4 o;
            o[0] = f2bf(v.x); o[1] = f2bf(v.y); o[2] = f2bf(v.z); o[3] = f2bf(v.w);
            *(u16x4*)(xb + i) = o;
        }
    } else if (b < BA + BB) {
        long i = ((long)(b - BA) * 256 + tid) * 4;   // i < 9*16384
        if (i < 9L * 16384) {
            const float* srcp = (i < 8L * 16384) ? (weight + i) : (slw + (i - 8L * 16384));
            float4 v = *(const float4*)srcp;
            u16x4 o;
            o[0] = f2bf(v.x); o[1] = f2bf(v.y); o[2] = f2bf(v.z); o[3] = f2bf(v.w);
            *(u16x4*)(Wb + i) = o;
        }
    } else {
        int j = (b - BA - BB) * 256 + tid;
        if (j < N) cursor[j] = 0;
    }
}

// ---------- MFMA GEMM (R5-exact gemm2): co-resident persistent blocks ----------
// grid (56,1,9) x 256 thr (4 waves), __launch_bounds__(256,2). Wave: 64x64.
// B-frags in registers via scalar loads from ROW-MAJOR Wb (loaded once/block),
// A-frags direct from global (lockstep z keeps xb L2/L3-hot),
// wave-private LDS epilogue slab. No __syncthreads.
// [measured R5: 41.2 us, FETCH 7.5 MB, WRITE 112.5 MB, 0 LDS conflicts]
__global__ __launch_bounds__(256, 2) void mfma_gemm2(
    const u16* __restrict__ xb,    // [N][128] bf16
    const u16* __restrict__ Wb,    // [9][128][128] bf16, row-major [k][col]
    const float* __restrict__ bias,
    u16* __restrict__ hr,          // [9][N][128] bf16
    int N, int ntiles)
{
    __shared__ u16 slab[4][16 * 68];   // per-wave epilogue staging (stride 68)

    const int tid   = threadIdx.x;
    const int z     = blockIdx.z;
    const int wv    = tid >> 6;
    const int lane  = tid & 63;
    const int q     = lane >> 4;       // quad
    const int l     = lane & 15;
    const int mbase = (wv >> 1) * 64;  // row slab within 128-tile
    const int cbase = (wv & 1) * 64;   // col slab

    const u16* Wz = Wb + (size_t)z * 128 * 128;

    // B-frags: B[nt][kc] lane holds W[k = kc*32 + q*8 + j][cbase + nt*16 + l]
    u16x8 Bf[4][4];
    #pragma unroll
    for (int nt = 0; nt < 4; ++nt) {
        const int col = cbase + nt * 16 + l;
        #pragma unroll
        for (int kc = 0; kc < 4; ++kc) {
            const int k0 = kc * 32 + q * 8;
            #pragma unroll
            for (int j = 0; j < 8; ++j)
                Bf[nt][kc][j] = Wz[(k0 + j) * 128 + col];
        }
    }

    // bias per column tile (z==8 only)
    float bv[4];
    #pragma unroll
    for (int nt = 0; nt < 4; ++nt)
        bv[nt] = (z == 8) ? bias[cbase + nt * 16 + l] : 0.f;

    u16* slabw = &slab[wv][0];

    for (int tile = blockIdx.x; tile < ntiles; tile += gridDim.x) {
        const int n0 = tile * 128;

        f32x4 acc[4][4] = {};

        #pragma unroll
        for (int kc = 0; kc < 4; ++kc) {
            const int k0 = kc * 32 + q * 8;
            u16x8 a[4];
            #pragma unroll
            for (int mt = 0; mt < 4; ++mt) {
                const int row = n0 + mbase + mt * 16 + l;
                u16x8 v = {};
                if (row < N) v = *(const u16x8*)(xb + (size_t)row * 128 + k0);
                a[mt] = v;
            }
            #pragma unroll
            for (int nt = 0; nt < 4; ++nt) {
                bf16x8 b = __builtin_bit_cast(bf16x8, Bf[nt][kc]);
                #pragma unroll
                for (int mt = 0; mt < 4; ++mt) {
                    acc[mt][nt] = __builtin_amdgcn_mfma_f32_16x16x32_bf16(
                        __builtin_bit_cast(bf16x8, a[mt]), b, acc[mt][nt], 0, 0, 0);
                }
            }
        }

        // epilogue: per m-tile, stage 16x64 slab in LDS, read back coalesced
        u16* hrz = hr + ((size_t)z * N) * 128;
        #pragma unroll
        for (int mt = 0; mt < 4; ++mt) {
            #pragma unroll
            for (int nt = 0; nt < 4; ++nt) {
                const int col = nt * 16 + l;
                #pragma unroll
                for (int j = 0; j < 4; ++j) {
                    slabw[(q * 4 + j) * 68 + col] = f2bf(acc[mt][nt][j] + bv[nt]);
                }
            }
            const int srow = lane >> 3;          // 0..7
            const int scol = (lane & 7) * 8;     // 0..56
            #pragma unroll
            for (int h = 0; h < 2; ++h) {
                const int r = h * 8 + srow;
                const int grow = n0 + mbase + mt * 16 + r;
                if (grow < N) {
                    u16x8 v = *(const u16x8*)&slabw[r * 68 + scol];
                    *(u16x8*)(hrz + (size_t)grow * 128 + cbase + scol) = v;
                }
            }
        }
    }
}

// ---------- CSR build ----------
__global__ __launch_bounds__(256) void k_hist(
    const int* __restrict__ dst, int* __restrict__ deg, int E)
{
    int e = blockIdx.x * blockDim.x + threadIdx.x;
    if (e < E) atomicAdd(&deg[dst[e]], 1);
}

__global__ __launch_bounds__(256) void k_scan1(
    const int* __restrict__ deg, int* __restrict__ local,
    int* __restrict__ bsum, int n)
{
    __shared__ int s[256];
    const int t = threadIdx.x;
    const int base = blockIdx.x * SCAN_ELEMS + t * 8;
    int v[8];
    int sum = 0;
    #pragma unroll
    for (int j = 0; j < 8; ++j) {
        int i = base + j;
        v[j] = (i < n) ? deg[i] : 0;
        sum += v[j];
    }
    s[t] = sum;
    __syncthreads();
    #pragma unroll
    for (int off = 1; off < 256; off <<= 1) {
        int y = (t >= off) ? s[t - off] : 0;
        __syncthreads();
        s[t] += y;
        __syncthreads();
    }
    int run = s[t] - sum;
    #pragma unroll
    for (int j = 0; j < 8; ++j) {
        int i = base + j;
        if (i < n) local[i] = run;
        run += v[j];
    }
    if (t == 255) bsum[blockIdx.x] = s[255];
}

// merged scan2+scan3: each block re-scans bsum (<=256 entries) in LDS,
// applies its block offset, writes row_ptr and cursor; block 0 writes total.
__global__ __launch_bounds__(256) void k_scan23(
    int* __restrict__ row_ptr, const int* __restrict__ bsum,
    int* __restrict__ cursor, int B, int n)
{
    __shared__ int s[256];
    const int t = threadIdx.x;
    int v = (t < B) ? bsum[t] : 0;
    s[t] = v;
    __syncthreads();
    #pragma unroll
    for (int off = 1; off < 256; off <<= 1) {
        int y = (t >= off) ? s[t - off] : 0;
        __syncthreads();
        s[t] += y;
        __syncthreads();
    }
    const int myoff = (blockIdx.x == 0) ? 0 : s[blockIdx.x - 1];
    const int total = s[255];
    const int base = blockIdx.x * SCAN_ELEMS + t * 8;
    #pragma unroll
    for (int j = 0; j < 8; ++j) {
        int i = base + j;
        if (i < n) {
            int val = row_ptr[i] + myoff;
            row_ptr[i] = val;
            cursor[i] = val;
        }
    }
    if (blockIdx.x == 0 && t == 0) row_ptr[n] = total;
}

__global__ __launch_bounds__(256) void k_fill(
    const int* __restrict__ src, const int* __restrict__ dst,
    const int* __restrict__ et, int* __restrict__ cursor,
    int* __restrict__ packed, int E)
{
    int e = blockIdx.x * blockDim.x + threadIdx.x;
    if (e >= E) return;
    int pos = atomicAdd(&cursor[dst[e]], 1);
    packed[pos] = (et[e] << 17) | src[e];
}

// ---------- pull-based aggregate: 16-lane groups (u16x8/lane), 4-deep MLP ----------
__global__ __launch_bounds__(256) void gather_bf16(
    const u16* __restrict__ hr,      // [8][N][128] bf16
    const u16* __restrict__ hself,   // [N][128] bf16 (x@slw + bias)
    const int* __restrict__ row_ptr, const int* __restrict__ packed,
    float* __restrict__ out, int Nn, int N)
{
    int g = blockIdx.x * 16 + (threadIdx.x >> 4);
    int lane = threadIdx.x & 15;
    if (g >= Nn) return;
    const int beg = row_ptr[g];
    const int end = row_ptr[g + 1];
    const int lo = lane * 8;

    u16x8 sv = *(const u16x8*)(hself + (size_t)g * 128 + lo);
    float a[8], b[8], c[8], d[8];
    #pragma unroll
    for (int j = 0; j < 8; ++j) { a[j] = bf2f(sv[j]); b[j] = 0.f; c[j] = 0.f; d[j] = 0.f; }

    int k = beg;
    for (; k + 4 <= end; k += 4) {
        int p0 = packed[k], p1 = packed[k + 1], p2 = packed[k + 2], p3 = packed[k + 3];
        u16x8 v0 = *(const u16x8*)(hr + ((size_t)(p0 >> 17) * N + (p0 & 0x1FFFF)) * 128 + lo);
        u16x8 v1 = *(const u16x8*)(hr + ((size_t)(p1 >> 17) * N + (p1 & 0x1FFFF)) * 128 + lo);
        u16x8 v2 = *(const u16x8*)(hr + ((size_t)(p2 >> 17) * N + (p2 & 0x1FFFF)) * 128 + lo);
        u16x8 v3 = *(const u16x8*)(hr + ((size_t)(p3 >> 17) * N + (p3 & 0x1FFFF)) * 128 + lo);
        #pragma unroll
        for (int j = 0; j < 8; ++j) {
            a[j] += bf2f(v0[j]); b[j] += bf2f(v1[j]);
            c[j] += bf2f(v2[j]); d[j] += bf2f(v3[j]);
        }
    }
    for (; k < end; ++k) {
        int p = packed[k];
        u16x8 v = *(const u16x8*)(hr + ((size_t)(p >> 17) * N + (p & 0x1FFFF)) * 128 + lo);
        #pragma unroll
        for (int j = 0; j < 8; ++j) a[j] += bf2f(v[j]);
    }
    #pragma unroll
    for (int j = 0; j < 8; ++j) a[j] = fmaxf(a[j] + b[j] + c[j] + d[j], 0.f);

    float* op = out + (size_t)g * 128 + lo;
    *(float4*)op       = make_float4(a[0], a[1], a[2], a[3]);
    *(float4*)(op + 4) = make_float4(a[4], a[5], a[6], a[7]);
}

// ---------- fp32 fallback kernels ----------
__global__ __launch_bounds__(256) void gemm128(
    const float* __restrict__ x, const float* __restrict__ W,
    const float* __restrict__ bias, float* __restrict__ out, int N)
{
    __shared__ float Ws[IN_DIM * OUT_DIM];
    __shared__ float xs[16][IN_DIM];

    const float* Wz = W + (size_t)blockIdx.z * IN_DIM * OUT_DIM;
    float* outz = out + (size_t)blockIdx.z * (size_t)N * OUT_DIM;

    {
        const float4* s4 = (const float4*)Wz;
        float4* d4 = (float4*)Ws;
        for (int i = threadIdx.x; i < IN_DIM * OUT_DIM / 4; i += 256)
            d4[i] = s4[i];
    }

    const int tid = threadIdx.x;
    const int nl = (tid >> 5) * 2;
    const int og = (tid & 31) * 4;

    float4 b4 = make_float4(0.f, 0.f, 0.f, 0.f);
    if (bias) b4 = *(const float4*)&bias[og];

    const int nchunks = (N + 15) / 16;
    for (int chunk = blockIdx.x; chunk < nchunks; chunk += gridDim.x) {
        const int n0 = chunk * 16;
        const int rows = min(16, N - n0);
        __syncthreads();
        {
            const float4* xsrc = (const float4*)(x + (size_t)n0 * IN_DIM);
            float4* xdst = (float4*)&xs[0][0];
            const int n4 = rows * (IN_DIM / 4);
            for (int i = tid; i < n4; i += 256) xdst[i] = xsrc[i];
        }
        __syncthreads();

        if (nl < rows) {
            float a00 = 0.f, a01 = 0.f, a02 = 0.f, a03 = 0.f;
            float a10 = 0.f, a11 = 0.f, a12 = 0.f, a13 = 0.f;
            #pragma unroll 8
            for (int d = 0; d < IN_DIM; ++d) {
                const float4 w4 = *(const float4*)&Ws[d * OUT_DIM + og];
                const float xa = xs[nl][d];
                const float xb = xs[nl + 1][d];
                a00 += xa * w4.x; a01 += xa * w4.y; a02 += xa * w4.z; a03 += xa * w4.w;
                a10 += xb * w4.x; a11 += xb * w4.y; a12 += xb * w4.z; a13 += xb * w4.w;
            }
            float4 r0 = make_float4(a00 + b4.x, a01 + b4.y, a02 + b4.z, a03 + b4.w);
            *(float4*)&outz[(size_t)(n0 + nl) * OUT_DIM + og] = r0;
            if (nl + 1 < rows) {
                float4 r1 = make_float4(a10 + b4.x, a11 + b4.y, a12 + b4.z, a13 + b4.w);
                *(float4*)&outz[(size_t)(n0 + nl + 1) * OUT_DIM + og] = r1;
            }
        }
    }
}

__global__ __launch_bounds__(256) void edge_direct(
    const float* __restrict__ x, const float* __restrict__ W,
    const int* __restrict__ src, const int* __restrict__ dst,
    const int* __restrict__ et, float* __restrict__ out, int E)
{
    long t = (long)blockIdx.x * blockDim.x + threadIdx.x;
    long e = t >> 6;
    int lane = (int)(t & 63);
    if (e >= E) return;
    int s = src[e], d = dst[e], r = et[e];
    const float* xr = x + (long)s * IN_DIM;
    float2 xv = *(const float2*)(xr + lane * 2);
    const float* Wr = W + (long)r * IN_DIM * OUT_DIM;
    const int o0 = lane * 2;
    float a0 = 0.f, a1 = 0.f;
    #pragma unroll 8
    for (int dd = 0; dd < 64; ++dd) {
        float xa = __shfl(xv.x, dd);
        float xb = __shfl(xv.y, dd);
        a0 += xa * Wr[(2 * dd) * OUT_DIM + o0]     + xb * Wr[(2 * dd + 1) * OUT_DIM + o0];
        a1 += xa * Wr[(2 * dd) * OUT_DIM + o0 + 1] + xb * Wr[(2 * dd + 1) * OUT_DIM + o0 + 1];
    }
    atomicAdd(out + (long)d * OUT_DIM + o0, a0);
    atomicAdd(out + (long)d * OUT_DIM + o0 + 1, a1);
}

__global__ __launch_bounds__(256) void relu_k(float* __restrict__ out, long n4)
{
    long i = (long)blockIdx.x * blockDim.x + threadIdx.x;
    if (i >= n4) return;
    float4 v = ((float4*)out)[i];
    v.x = fmaxf(v.x, 0.f); v.y = fmaxf(v.y, 0.f);
    v.z = fmaxf(v.z, 0.f); v.w = fmaxf(v.w, 0.f);
    ((float4*)out)[i] = v;
}

static inline size_t align256(size_t x) { return (x + 255) & ~(size_t)255; }

extern "C" void kernel_launch(void* const* d_in, const int* in_sizes, int n_in,
                              void* d_out, int out_size, void* d_ws, size_t ws_size,
                              hipStream_t stream)
{
    const float* x      = (const float*)d_in[0];
    const float* weight = (const float*)d_in[1];
    const float* slw    = (const float*)d_in[2];
    const float* bias   = (const float*)d_in[3];
    const int*   ei     = (const int*)d_in[4];
    const int*   et     = (const int*)d_in[5];

    const int N = in_sizes[0] / IN_DIM;
    const int E = in_sizes[5];
    const int* src  = ei;
    const int* dstp = ei + E;

    float* out = (float*)d_out;

    // workspace layout (bf16 path)
    size_t off = 0;
    const size_t xb_off   = off; off += align256((size_t)N * 128 * 2);
    const size_t wb_off   = off; off += align256((size_t)9 * 128 * 128 * 2);
    const size_t hr_off   = off; off += align256((size_t)9 * N * 128 * 2);
    const size_t rp_off   = off; off += align256((size_t)(N + 1) * 4);
    const size_t cur_off  = off; off += align256((size_t)N * 4);
    const size_t pk_off   = off; off += align256((size_t)E * 4);
    const size_t bs_off   = off; off += align256(256 * 4);
    const size_t need_bf16 = off;

    const int scanB = (N + SCAN_ELEMS - 1) / SCAN_ELEMS;

    if (ws_size >= need_bf16 && N <= (1 << 17) && scanB <= 256) {
        char* base   = (char*)d_ws;
        u16* xb      = (u16*)(base + xb_off);
        u16* Wb      = (u16*)(base + wb_off);
        u16* hr      = (u16*)(base + hr_off);
        int* row_ptr = (int*)(base + rp_off);
        int* cursor  = (int*)(base + cur_off);
        int* packed  = (int*)(base + pk_off);
        int* bsum    = (int*)(base + bs_off);

        // fused prep: cast x, cast W (row-major), zero cursor
        const int BA = (int)(((long)N * 128 / 4 + 255) / 256);
        const int BB = (9 * 16384 / 4 + 255) / 256;   // 144
        const int BC = (N + 255) / 256;
        k_prep<<<dim3(BA + BB + BC), 256, 0, stream>>>(
            x, weight, slw, xb, Wb, cursor, N, BA, BB);

        // CSR build (deg lives in cursor)
        k_hist<<<dim3((E + 255) / 256), 256, 0, stream>>>(dstp, cursor, E);
        k_scan1<<<dim3(scanB), 256, 0, stream>>>(cursor, row_ptr, bsum, N);
        k_scan23<<<dim3(scanB), 256, 0, stream>>>(row_ptr, bsum, cursor, scanB, N);
        k_fill<<<dim3((E + 255) / 256), 256, 0, stream>>>(src, dstp, et, cursor, packed, E);

        // all 9 transforms via MFMA: co-resident persistent grid (504 blocks), R5-exact
        const int ntiles = (N + 127) / 128;
        const int gx = ntiles < 56 ? ntiles : 56;
        mfma_gemm2<<<dim3(gx, 1, 9), 256, 0, stream>>>(xb, Wb, bias, hr, N, ntiles);

        // aggregate + self + relu -> out (16-lane groups, 4-deep MLP)
        gather_bf16<<<dim3((N + 15) / 16), 256, 0, stream>>>(
            hr, hr + (size_t)8 * N * 128, row_ptr, packed, out, N, N);
    } else if (ws_size >= (size_t)NUM_RELS * N * 128 * 4) {
        gemm128<<<dim3(512, 1, 1), 256, 0, stream>>>(x, slw, bias, out, N);
        long nt = (long)E * 64;
        edge_direct<<<dim3((nt + 255) / 256), 256, 0, stream>>>(x, weight, src, dstp, et, out, E);
        long n4 = (long)N * OUT_DIM / 4;
        relu_k<<<dim3((n4 + 255) / 256), 256, 0, stream>>>(out, n4);
    } else {
        gemm128<<<dim3(512, 1, 1), 256, 0, stream>>>(x, slw, bias, out, N);
        long nt = (long)E * 64;
        edge_direct<<<dim3((nt + 255) / 256), 256, 0, stream>>>(x, weight, src, dstp, et, out, E);
        long n4 = (long)N * OUT_DIM / 4;
        relu_k<<<dim3((n4 + 255) / 256), 256, 0, stream>>>(out, n4);
    }
}

// Round 10
// 210.436 us; speedup vs baseline: 1.1244x; 1.0028x over previous
//
#include <hip/hip_runtime.h>

#define IN_DIM 128
#define OUT_DIM 128
#define NUM_RELS 8
#define SCAN_ELEMS 2048   // per block, 256 thr x 8

typedef unsigned short u16;
typedef u16 u16x8 __attribute__((ext_vector_type(8)));
typedef u16 u16x4 __attribute__((ext_vector_type(4)));
typedef __bf16 bf16x8 __attribute__((ext_vector_type(8)));
typedef float f32x4 __attribute__((ext_vector_type(4)));

__device__ __forceinline__ u16 f2bf(float f) {
    unsigned u = __float_as_uint(f);
    u += 0x7FFF + ((u >> 16) & 1);      // RNE
    return (u16)(u >> 16);
}
__device__ __forceinline__ float bf2f(u16 h) {
    return __uint_as_float((unsigned)h << 16);
}

// ---------- fused prep: cast x -> bf16, cast W+slw -> Wb (ROW-MAJOR), zero cursor ----
__global__ __launch_bounds__(256) void k_prep(
    const float* __restrict__ x, const float* __restrict__ weight,
    const float* __restrict__ slw,
    u16* __restrict__ xb, u16* __restrict__ Wb, int* __restrict__ cursor,
    int N, int BA, int BB)
{
    const int b = blockIdx.x;
    const int tid = threadIdx.x;
    if (b < BA) {
        long i = ((long)b * 256 + tid) * 4;
        if (i < (long)N * 128) {
            float4 v = *(const float4*)(x + i);
            u16x4 o;
            o[0] = f2bf(v.x); o[1] = f2bf(v.y); o[2] = f2bf(v.z); o[3] = f2bf(v.w);
            *(u16x4*)(xb + i) = o;
        }
    } else if (b < BA + BB) {
        long i = ((long)(b - BA) * 256 + tid) * 4;   // i < 9*16384
        if (i < 9L * 16384) {
            const float* srcp = (i < 8L * 16384) ? (weight + i) : (slw + (i - 8L * 16384));
            float4 v = *(const float4*)srcp;
            u16x4 o;
            o[0] = f2bf(v.x); o[1] = f2bf(v.y); o[2] = f2bf(v.z); o[3] = f2bf(v.w);
            *(u16x4*)(Wb + i) = o;
        }
    } else {
        int j = (b - BA - BB) * 256 + tid;
        if (j < N) cursor[j] = 0;
    }
}

// ---------- MFMA GEMM (R5-exact, FROZEN): co-resident persistent blocks ----------
// grid (56,1,9) x 256 thr (4 waves), __launch_bounds__(256,2). Wave: 64x64.
// B-frags in registers via scalar loads from ROW-MAJOR Wb (loaded once/block),
// A-frags direct from global (lockstep z keeps xb L2/L3-hot),
// wave-private LDS epilogue slab. No __syncthreads.
// [measured R5/R9: 41.2 us, FETCH 7465 KB, WRITE 112500 KB, 0 LDS conflicts.
//  DO NOT change grid/bounds/W-layout: R6(1-tile/block)=66us FETCH 57MB,
//  R7(grid756,b3,WbT)=63us 69MB, R8(grid504,b3,WbT)=60us 44MB.]
__global__ __launch_bounds__(256, 2) void mfma_gemm2(
    const u16* __restrict__ xb,    // [N][128] bf16
    const u16* __restrict__ Wb,    // [9][128][128] bf16, row-major [k][col]
    const float* __restrict__ bias,
    u16* __restrict__ hr,          // [9][N][128] bf16
    int N, int ntiles)
{
    __shared__ u16 slab[4][16 * 68];   // per-wave epilogue staging (stride 68)

    const int tid   = threadIdx.x;
    const int z     = blockIdx.z;
    const int wv    = tid >> 6;
    const int lane  = tid & 63;
    const int q     = lane >> 4;       // quad
    const int l     = lane & 15;
    const int mbase = (wv >> 1) * 64;  // row slab within 128-tile
    const int cbase = (wv & 1) * 64;   // col slab

    const u16* Wz = Wb + (size_t)z * 128 * 128;

    // B-frags: B[nt][kc] lane holds W[k = kc*32 + q*8 + j][cbase + nt*16 + l]
    u16x8 Bf[4][4];
    #pragma unroll
    for (int nt = 0; nt < 4; ++nt) {
        const int col = cbase + nt * 16 + l;
        #pragma unroll
        for (int kc = 0; kc < 4; ++kc) {
            const int k0 = kc * 32 + q * 8;
            #pragma unroll
            for (int j = 0; j < 8; ++j)
                Bf[nt][kc][j] = Wz[(k0 + j) * 128 + col];
        }
    }

    // bias per column tile (z==8 only)
    float bv[4];
    #pragma unroll
    for (int nt = 0; nt < 4; ++nt)
        bv[nt] = (z == 8) ? bias[cbase + nt * 16 + l] : 0.f;

    u16* slabw = &slab[wv][0];

    for (int tile = blockIdx.x; tile < ntiles; tile += gridDim.x) {
        const int n0 = tile * 128;

        f32x4 acc[4][4] = {};

        #pragma unroll
        for (int kc = 0; kc < 4; ++kc) {
            const int k0 = kc * 32 + q * 8;
            u16x8 a[4];
            #pragma unroll
            for (int mt = 0; mt < 4; ++mt) {
                const int row = n0 + mbase + mt * 16 + l;
                u16x8 v = {};
                if (row < N) v = *(const u16x8*)(xb + (size_t)row * 128 + k0);
                a[mt] = v;
            }
            #pragma unroll
            for (int nt = 0; nt < 4; ++nt) {
                bf16x8 b = __builtin_bit_cast(bf16x8, Bf[nt][kc]);
                #pragma unroll
                for (int mt = 0; mt < 4; ++mt) {
                    acc[mt][nt] = __builtin_amdgcn_mfma_f32_16x16x32_bf16(
                        __builtin_bit_cast(bf16x8, a[mt]), b, acc[mt][nt], 0, 0, 0);
                }
            }
        }

        // epilogue: per m-tile, stage 16x64 slab in LDS, read back coalesced
        u16* hrz = hr + ((size_t)z * N) * 128;
        #pragma unroll
        for (int mt = 0; mt < 4; ++mt) {
            #pragma unroll
            for (int nt = 0; nt < 4; ++nt) {
                const int col = nt * 16 + l;
                #pragma unroll
                for (int j = 0; j < 4; ++j) {
                    slabw[(q * 4 + j) * 68 + col] = f2bf(acc[mt][nt][j] + bv[nt]);
                }
            }
            const int srow = lane >> 3;          // 0..7
            const int scol = (lane & 7) * 8;     // 0..56
            #pragma unroll
            for (int h = 0; h < 2; ++h) {
                const int r = h * 8 + srow;
                const int grow = n0 + mbase + mt * 16 + r;
                if (grow < N) {
                    u16x8 v = *(const u16x8*)&slabw[r * 68 + scol];
                    *(u16x8*)(hrz + (size_t)grow * 128 + cbase + scol) = v;
                }
            }
        }
    }
}

// ---------- CSR build ----------
__global__ __launch_bounds__(256) void k_hist(
    const int* __restrict__ dst, int* __restrict__ deg, int E)
{
    int e = blockIdx.x * blockDim.x + threadIdx.x;
    if (e < E) atomicAdd(&deg[dst[e]], 1);
}

__global__ __launch_bounds__(256) void k_scan1(
    const int* __restrict__ deg, int* __restrict__ local,
    int* __restrict__ bsum, int n)
{
    __shared__ int s[256];
    const int t = threadIdx.x;
    const int base = blockIdx.x * SCAN_ELEMS + t * 8;
    int v[8];
    int sum = 0;
    #pragma unroll
    for (int j = 0; j < 8; ++j) {
        int i = base + j;
        v[j] = (i < n) ? deg[i] : 0;
        sum += v[j];
    }
    s[t] = sum;
    __syncthreads();
    #pragma unroll
    for (int off = 1; off < 256; off <<= 1) {
        int y = (t >= off) ? s[t - off] : 0;
        __syncthreads();
        s[t] += y;
        __syncthreads();
    }
    int run = s[t] - sum;
    #pragma unroll
    for (int j = 0; j < 8; ++j) {
        int i = base + j;
        if (i < n) local[i] = run;
        run += v[j];
    }
    if (t == 255) bsum[blockIdx.x] = s[255];
}

// merged scan2+scan3: each block re-scans bsum (<=256 entries) in LDS,
// applies its block offset, writes row_ptr and cursor; block 0 writes total.
__global__ __launch_bounds__(256) void k_scan23(
    int* __restrict__ row_ptr, const int* __restrict__ bsum,
    int* __restrict__ cursor, int B, int n)
{
    __shared__ int s[256];
    const int t = threadIdx.x;
    int v = (t < B) ? bsum[t] : 0;
    s[t] = v;
    __syncthreads();
    #pragma unroll
    for (int off = 1; off < 256; off <<= 1) {
        int y = (t >= off) ? s[t - off] : 0;
        __syncthreads();
        s[t] += y;
        __syncthreads();
    }
    const int myoff = (blockIdx.x == 0) ? 0 : s[blockIdx.x - 1];
    const int total = s[255];
    const int base = blockIdx.x * SCAN_ELEMS + t * 8;
    #pragma unroll
    for (int j = 0; j < 8; ++j) {
        int i = base + j;
        if (i < n) {
            int val = row_ptr[i] + myoff;
            row_ptr[i] = val;
            cursor[i] = val;
        }
    }
    if (blockIdx.x == 0 && t == 0) row_ptr[n] = total;
}

__global__ __launch_bounds__(256) void k_fill(
    const int* __restrict__ src, const int* __restrict__ dst,
    const int* __restrict__ et, int* __restrict__ cursor,
    int* __restrict__ packed, int E)
{
    int e = blockIdx.x * blockDim.x + threadIdx.x;
    if (e >= E) return;
    int pos = atomicAdd(&cursor[dst[e]], 1);
    packed[pos] = (et[e] << 17) | src[e];
}

// ---------- pull-based aggregate: 16-lane groups (u16x8/lane), 8-deep MLP ----------
__global__ __launch_bounds__(256) void gather_bf16(
    const u16* __restrict__ hr,      // [8][N][128] bf16
    const u16* __restrict__ hself,   // [N][128] bf16 (x@slw + bias)
    const int* __restrict__ row_ptr, const int* __restrict__ packed,
    float* __restrict__ out, int Nn, int N)
{
    int g = blockIdx.x * 16 + (threadIdx.x >> 4);
    int lane = threadIdx.x & 15;
    if (g >= Nn) return;
    const int beg = row_ptr[g];
    const int end = row_ptr[g + 1];
    const int lo = lane * 8;

    u16x8 sv = *(const u16x8*)(hself + (size_t)g * 128 + lo);
    float a[8], b[8], c[8], d[8];
    #pragma unroll
    for (int j = 0; j < 8; ++j) { a[j] = bf2f(sv[j]); b[j] = 0.f; c[j] = 0.f; d[j] = 0.f; }

    int k = beg;
    // 8 loads in flight per iteration, 4 independent accumulation chains
    for (; k + 8 <= end; k += 8) {
        int p0 = packed[k],     p1 = packed[k + 1], p2 = packed[k + 2], p3 = packed[k + 3];
        int p4 = packed[k + 4], p5 = packed[k + 5], p6 = packed[k + 6], p7 = packed[k + 7];
        u16x8 v0 = *(const u16x8*)(hr + ((size_t)(p0 >> 17) * N + (p0 & 0x1FFFF)) * 128 + lo);
        u16x8 v1 = *(const u16x8*)(hr + ((size_t)(p1 >> 17) * N + (p1 & 0x1FFFF)) * 128 + lo);
        u16x8 v2 = *(const u16x8*)(hr + ((size_t)(p2 >> 17) * N + (p2 & 0x1FFFF)) * 128 + lo);
        u16x8 v3 = *(const u16x8*)(hr + ((size_t)(p3 >> 17) * N + (p3 & 0x1FFFF)) * 128 + lo);
        u16x8 v4 = *(const u16x8*)(hr + ((size_t)(p4 >> 17) * N + (p4 & 0x1FFFF)) * 128 + lo);
        u16x8 v5 = *(const u16x8*)(hr + ((size_t)(p5 >> 17) * N + (p5 & 0x1FFFF)) * 128 + lo);
        u16x8 v6 = *(const u16x8*)(hr + ((size_t)(p6 >> 17) * N + (p6 & 0x1FFFF)) * 128 + lo);
        u16x8 v7 = *(const u16x8*)(hr + ((size_t)(p7 >> 17) * N + (p7 & 0x1FFFF)) * 128 + lo);
        #pragma unroll
        for (int j = 0; j < 8; ++j) {
            a[j] += bf2f(v0[j]); b[j] += bf2f(v1[j]);
            c[j] += bf2f(v2[j]); d[j] += bf2f(v3[j]);
            a[j] += bf2f(v4[j]); b[j] += bf2f(v5[j]);
            c[j] += bf2f(v6[j]); d[j] += bf2f(v7[j]);
        }
    }
    for (; k + 4 <= end; k += 4) {
        int p0 = packed[k], p1 = packed[k + 1], p2 = packed[k + 2], p3 = packed[k + 3];
        u16x8 v0 = *(const u16x8*)(hr + ((size_t)(p0 >> 17) * N + (p0 & 0x1FFFF)) * 128 + lo);
        u16x8 v1 = *(const u16x8*)(hr + ((size_t)(p1 >> 17) * N + (p1 & 0x1FFFF)) * 128 + lo);
        u16x8 v2 = *(const u16x8*)(hr + ((size_t)(p2 >> 17) * N + (p2 & 0x1FFFF)) * 128 + lo);
        u16x8 v3 = *(const u16x8*)(hr + ((size_t)(p3 >> 17) * N + (p3 & 0x1FFFF)) * 128 + lo);
        #pragma unroll
        for (int j = 0; j < 8; ++j) {
            a[j] += bf2f(v0[j]); b[j] += bf2f(v1[j]);
            c[j] += bf2f(v2[j]); d[j] += bf2f(v3[j]);
        }
    }
    for (; k < end; ++k) {
        int p = packed[k];
        u16x8 v = *(const u16x8*)(hr + ((size_t)(p >> 17) * N + (p & 0x1FFFF)) * 128 + lo);
        #pragma unroll
        for (int j = 0; j < 8; ++j) a[j] += bf2f(v[j]);
    }
    #pragma unroll
    for (int j = 0; j < 8; ++j) a[j] = fmaxf(a[j] + b[j] + c[j] + d[j], 0.f);

    float* op = out + (size_t)g * 128 + lo;
    *(float4*)op       = make_float4(a[0], a[1], a[2], a[3]);
    *(float4*)(op + 4) = make_float4(a[4], a[5], a[6], a[7]);
}

// ---------- fp32 fallback kernels ----------
__global__ __launch_bounds__(256) void gemm128(
    const float* __restrict__ x, const float* __restrict__ W,
    const float* __restrict__ bias, float* __restrict__ out, int N)
{
    __shared__ float Ws[IN_DIM * OUT_DIM];
    __shared__ float xs[16][IN_DIM];

    const float* Wz = W + (size_t)blockIdx.z * IN_DIM * OUT_DIM;
    float* outz = out + (size_t)blockIdx.z * (size_t)N * OUT_DIM;

    {
        const float4* s4 = (const float4*)Wz;
        float4* d4 = (float4*)Ws;
        for (int i = threadIdx.x; i < IN_DIM * OUT_DIM / 4; i += 256)
            d4[i] = s4[i];
    }

    const int tid = threadIdx.x;
    const int nl = (tid >> 5) * 2;
    const int og = (tid & 31) * 4;

    float4 b4 = make_float4(0.f, 0.f, 0.f, 0.f);
    if (bias) b4 = *(const float4*)&bias[og];

    const int nchunks = (N + 15) / 16;
    for (int chunk = blockIdx.x; chunk < nchunks; chunk += gridDim.x) {
        const int n0 = chunk * 16;
        const int rows = min(16, N - n0);
        __syncthreads();
        {
            const float4* xsrc = (const float4*)(x + (size_t)n0 * IN_DIM);
            float4* xdst = (float4*)&xs[0][0];
            const int n4 = rows * (IN_DIM / 4);
            for (int i = tid; i < n4; i += 256) xdst[i] = xsrc[i];
        }
        __syncthreads();

        if (nl < rows) {
            float a00 = 0.f, a01 = 0.f, a02 = 0.f, a03 = 0.f;
            float a10 = 0.f, a11 = 0.f, a12 = 0.f, a13 = 0.f;
            #pragma unroll 8
            for (int d = 0; d < IN_DIM; ++d) {
                const float4 w4 = *(const float4*)&Ws[d * OUT_DIM + og];
                const float xa = xs[nl][d];
                const float xb = xs[nl + 1][d];
                a00 += xa * w4.x; a01 += xa * w4.y; a02 += xa * w4.z; a03 += xa * w4.w;
                a10 += xb * w4.x; a11 += xb * w4.y; a12 += xb * w4.z; a13 += xb * w4.w;
            }
            float4 r0 = make_float4(a00 + b4.x, a01 + b4.y, a02 + b4.z, a03 + b4.w);
            *(float4*)&outz[(size_t)(n0 + nl) * OUT_DIM + og] = r0;
            if (nl + 1 < rows) {
                float4 r1 = make_float4(a10 + b4.x, a11 + b4.y, a12 + b4.z, a13 + b4.w);
                *(float4*)&outz[(size_t)(n0 + nl + 1) * OUT_DIM + og] = r1;
            }
        }
    }
}

__global__ __launch_bounds__(256) void edge_direct(
    const float* __restrict__ x, const float* __restrict__ W,
    const int* __restrict__ src, const int* __restrict__ dst,
    const int* __restrict__ et, float* __restrict__ out, int E)
{
    long t = (long)blockIdx.x * blockDim.x + threadIdx.x;
    long e = t >> 6;
    int lane = (int)(t & 63);
    if (e >= E) return;
    int s = src[e], d = dst[e], r = et[e];
    const float* xr = x + (long)s * IN_DIM;
    float2 xv = *(const float2*)(xr + lane * 2);
    const float* Wr = W + (long)r * IN_DIM * OUT_DIM;
    const int o0 = lane * 2;
    float a0 = 0.f, a1 = 0.f;
    #pragma unroll 8
    for (int dd = 0; dd < 64; ++dd) {
        float xa = __shfl(xv.x, dd);
        float xb = __shfl(xv.y, dd);
        a0 += xa * Wr[(2 * dd) * OUT_DIM + o0]     + xb * Wr[(2 * dd + 1) * OUT_DIM + o0];
        a1 += xa * Wr[(2 * dd) * OUT_DIM + o0 + 1] + xb * Wr[(2 * dd + 1) * OUT_DIM + o0 + 1];
    }
    atomicAdd(out + (long)d * OUT_DIM + o0, a0);
    atomicAdd(out + (long)d * OUT_DIM + o0 + 1, a1);
}

__global__ __launch_bounds__(256) void relu_k(float* __restrict__ out, long n4)
{
    long i = (long)blockIdx.x * blockDim.x + threadIdx.x;
    if (i >= n4) return;
    float4 v = ((float4*)out)[i];
    v.x = fmaxf(v.x, 0.f); v.y = fmaxf(v.y, 0.f);
    v.z = fmaxf(v.z, 0.f); v.w = fmaxf(v.w, 0.f);
    ((float4*)out)[i] = v;
}

static inline size_t align256(size_t x) { return (x + 255) & ~(size_t)255; }

extern "C" void kernel_launch(void* const* d_in, const int* in_sizes, int n_in,
                              void* d_out, int out_size, void* d_ws, size_t ws_size,
                              hipStream_t stream)
{
    const float* x      = (const float*)d_in[0];
    const float* weight = (const float*)d_in[1];
    const float* slw    = (const float*)d_in[2];
    const float* bias   = (const float*)d_in[3];
    const int*   ei     = (const int*)d_in[4];
    const int*   et     = (const int*)d_in[5];

    const int N = in_sizes[0] / IN_DIM;
    const int E = in_sizes[5];
    const int* src  = ei;
    const int* dstp = ei + E;

    float* out = (float*)d_out;

    // workspace layout (bf16 path)
    size_t off = 0;
    const size_t xb_off   = off; off += align256((size_t)N * 128 * 2);
    const size_t wb_off   = off; off += align256((size_t)9 * 128 * 128 * 2);
    const size_t hr_off   = off; off += align256((size_t)9 * N * 128 * 2);
    const size_t rp_off   = off; off += align256((size_t)(N + 1) * 4);
    const size_t cur_off  = off; off += align256((size_t)N * 4);
    const size_t pk_off   = off; off += align256((size_t)E * 4);
    const size_t bs_off   = off; off += align256(256 * 4);
    const size_t need_bf16 = off;

    const int scanB = (N + SCAN_ELEMS - 1) / SCAN_ELEMS;

    if (ws_size >= need_bf16 && N <= (1 << 17) && scanB <= 256) {
        char* base   = (char*)d_ws;
        u16* xb      = (u16*)(base + xb_off);
        u16* Wb      = (u16*)(base + wb_off);
        u16* hr      = (u16*)(base + hr_off);
        int* row_ptr = (int*)(base + rp_off);
        int* cursor  = (int*)(base + cur_off);
        int* packed  = (int*)(base + pk_off);
        int* bsum    = (int*)(base + bs_off);

        // fused prep: cast x, cast W (row-major), zero cursor
        const int BA = (int)(((long)N * 128 / 4 + 255) / 256);
        const int BB = (9 * 16384 / 4 + 255) / 256;   // 144
        const int BC = (N + 255) / 256;
        k_prep<<<dim3(BA + BB + BC), 256, 0, stream>>>(
            x, weight, slw, xb, Wb, cursor, N, BA, BB);

        // GEMM immediately after prep (xb/Wb L2-hot); only depends on prep
        const int ntiles = (N + 127) / 128;
        const int gx = ntiles < 56 ? ntiles : 56;
        mfma_gemm2<<<dim3(gx, 1, 9), 256, 0, stream>>>(xb, Wb, bias, hr, N, ntiles);

        // CSR build right before gather (packed/cursor stay hot)
        k_hist<<<dim3((E + 255) / 256), 256, 0, stream>>>(dstp, cursor, E);
        k_scan1<<<dim3(scanB), 256, 0, stream>>>(cursor, row_ptr, bsum, N);
        k_scan23<<<dim3(scanB), 256, 0, stream>>>(row_ptr, bsum, cursor, scanB, N);
        k_fill<<<dim3((E + 255) / 256), 256, 0, stream>>>(src, dstp, et, cursor, packed, E);

        // aggregate + self + relu -> out (16-lane groups, 8-deep MLP)
        gather_bf16<<<dim3((N + 15) / 16), 256, 0, stream>>>(
            hr, hr + (size_t)8 * N * 128, row_ptr, packed, out, N, N);
    } else if (ws_size >= (size_t)NUM_RELS * N * 128 * 4) {
        gemm128<<<dim3(512, 1, 1), 256, 0, stream>>>(x, slw, bias, out, N);
        long nt = (long)E * 64;
        edge_direct<<<dim3((nt + 255) / 256), 256, 0, stream>>>(x, weight, src, dstp, et, out, E);
        long n4 = (long)N * OUT_DIM / 4;
        relu_k<<<dim3((n4 + 255) / 256), 256, 0, stream>>>(out, n4);
    } else {
        gemm128<<<dim3(512, 1, 1), 256, 0, stream>>>(x, slw, bias, out, N);
        long nt = (long)E * 64;
        edge_direct<<<dim3((nt + 255) / 256), 256, 0, stream>>>(x, weight, src, dstp, et, out, E);
        long n4 = (long)N * OUT_DIM / 4;
        relu_k<<<dim3((n4 + 255) / 256), 256, 0, stream>>>(out, n4);
    }
}